// Round 3
// baseline (874.657 us; speedup 1.0000x reference)
//
#include <hip/hip_runtime.h>
#include <hip/hip_bf16.h>

#define NSEQ 8192
#define CDIM 2048
#define NHEAD 16
#define HD 128

typedef short short8 __attribute__((ext_vector_type(8)));
typedef short short4v __attribute__((ext_vector_type(4)));
typedef float float4v __attribute__((ext_vector_type(4)));

__device__ __forceinline__ short f2bf(float f) {
    __hip_bfloat16 h = __float2bfloat16(f);
    return *reinterpret_cast<short*>(&h);
}

// async global->LDS, 16B per lane. LDS dest = wave-uniform base + lane*16B.
__device__ __forceinline__ void async_load16(const short* g, short* l) {
    __builtin_amdgcn_global_load_lds((const __attribute__((address_space(1))) void*)g,
                                     (__attribute__((address_space(3))) void*)l,
                                     16, 0, 0);
}

// ---------------------------------------------------------------------------
// fp32 -> bf16 conversion of x, Wq, Wk, Wv into workspace. 8 elems/thread.
// ---------------------------------------------------------------------------
#define X8 (33554432 / 8)   // x element-octets
#define W8 (4194304 / 8)    // per-W element-octets

__global__ __launch_bounds__(256) void cvt_all(
    const float* __restrict__ x, const float* __restrict__ wq,
    const float* __restrict__ wk, const float* __restrict__ wv,
    short* __restrict__ xb, short* __restrict__ wqb,
    short* __restrict__ wkb, short* __restrict__ wvb)
{
    const size_t i = (size_t)blockIdx.x * blockDim.x + threadIdx.x;
    const float* src;
    short* dst;
    size_t off;
    if (i < X8)              { src = x;  dst = xb;  off = i; }
    else if (i < X8 + W8)    { src = wq; dst = wqb; off = i - X8; }
    else if (i < X8 + 2*W8)  { src = wk; dst = wkb; off = i - X8 - W8; }
    else                     { src = wv; dst = wvb; off = i - X8 - 2*(size_t)W8; }
    const float4v a = ((const float4v*)src)[off * 2];
    const float4v b = ((const float4v*)src)[off * 2 + 1];
    short8 o;
    for (int j = 0; j < 4; j++) { o[j] = f2bf(a[j]); o[4 + j] = f2bf(b[j]); }
    ((short8*)dst)[off] = o;
}

// ---------------------------------------------------------------------------
// Fused QKV projection from bf16 copies: out = x @ W^T + b.
// m97-style: 128x128 tile, BK=32, 4 waves (2x2), global_load_lds width=16.
// Q -> fp32 d_out at [B][N][C] (final layout); K,V -> bf16 ws at [B][H][N][hd].
// blockIdx.y: [0..47] -> mat = y/16 (q,k,v), h = y%16 (n-tile == head).
// ---------------------------------------------------------------------------
__global__ __launch_bounds__(256, 2) void qkv_gemm(
    const short* __restrict__ x,
    const short* __restrict__ Wq, const float* __restrict__ bq,
    const short* __restrict__ Wk, const float* __restrict__ bk,
    const short* __restrict__ Wv, const float* __restrict__ bv,
    float* __restrict__ qout, short* __restrict__ kt, short* __restrict__ vt)
{
    __shared__ short As[128 * 32];
    __shared__ short Bs[128 * 32];

    const int tid  = threadIdx.x;
    const int wave = tid >> 6;
    const int lane = tid & 63;
    const int quad = lane >> 4;
    const int l15  = lane & 15;
    const int wm   = wave >> 1;   // 0..1: which 64-row half
    const int wn   = wave & 1;    // 0..1: which 64-col half

    const int m0  = blockIdx.x * 128;
    const int mat = blockIdx.y >> 4;
    const int h   = blockIdx.y & 15;
    const int n0  = h * HD;

    const short* W    = (mat == 0) ? Wq : (mat == 1) ? Wk : Wv;
    const float* bias = (mat == 0) ? bq : (mat == 1) ? bk : bv;

    const int srow = lane >> 2;        // staging: row within 16-row chunk
    const int scol = (lane & 3) * 8;   // staging: element col (0,8,16,24)

    const float4v fzero = {0.f, 0.f, 0.f, 0.f};
    float4v acc[4][4];
    for (int i = 0; i < 4; i++)
        for (int j = 0; j < 4; j++)
            acc[i][j] = fzero;

    for (int k0 = 0; k0 < CDIM; k0 += 32) {
        __syncthreads();
        for (int c = 0; c < 2; c++) {
            const int chunk = wave * 2 + c;              // 0..7 -> 16 rows each
            const int row   = chunk * 16 + srow;
            async_load16(x + (size_t)(m0 + row) * CDIM + k0 + scol, &As[chunk * 512]);
            async_load16(W + (size_t)(n0 + row) * CDIM + k0 + scol, &Bs[chunk * 512]);
        }
        __syncthreads();  // drains vmcnt for global_load_lds

        short8 af[4], bf[4];
        for (int i = 0; i < 4; i++)
            af[i] = *(const short8*)&As[(wm * 64 + i * 16 + l15) * 32 + quad * 8];
        for (int j = 0; j < 4; j++)
            bf[j] = *(const short8*)&Bs[(wn * 64 + j * 16 + l15) * 32 + quad * 8];
        for (int i = 0; i < 4; i++)
            for (int j = 0; j < 4; j++)
                acc[i][j] = __builtin_amdgcn_mfma_f32_16x16x32_bf16(af[i], bf[j],
                                                                    acc[i][j], 0, 0, 0);
    }

    float bvals[4];
    for (int j = 0; j < 4; j++)
        bvals[j] = bias[n0 + wn * 64 + j * 16 + l15];

    // C/D layout: row = quad*4 + r (m), col = l15 (n).
    for (int i = 0; i < 4; i++) {
        for (int j = 0; j < 4; j++) {
            const int d = wn * 64 + j * 16 + l15;
            for (int r = 0; r < 4; r++) {
                const int m   = m0 + wm * 64 + i * 16 + quad * 4 + r;
                const int b   = m >> 13;
                const int seq = m & (NSEQ - 1);
                const float v = acc[i][j][r] + bvals[j];
                if (mat == 0) {
                    // q: fp32, final [B][N][C] layout (lives in d_out)
                    qout[((size_t)(b * NSEQ + seq) << 11) + n0 + d] = v;
                } else {
                    short* outp = (mat == 1) ? kt : vt;
                    outp[(((size_t)(b * NHEAD + h) * NSEQ + seq) << 7) + d] = f2bf(v);
                }
            }
        }
    }
}

// ---------------------------------------------------------------------------
// Group-local causal attention, S2 shift via index arithmetic.
// Fully uniform control flow. 1 block per (b,h,g), 512 thr = 8 waves,
// wave w owns m-tiles {2w, 2w+1}. Causal mask applied arithmetically.
// q read fp32 from d_out (same rows this block later overwrites -> race-free).
// ---------------------------------------------------------------------------
__global__ __launch_bounds__(512, 2) void s2_attn(const float* qsrc,   // aliases out!
                                                  const short* __restrict__ kt,
                                                  const short* __restrict__ vt,
                                                  float* out)
{
    __shared__ short Ks[64 * 136];       // K chunk, row-major, +8 pad
    __shared__ short Vs[64 * 132];       // V chunk, row-major, +4 pad
    __shared__ short Ps[8][32 * 40];     // per-wave P: 32 q-rows x 32 keys

    const int bx = blockIdx.x;
    const int g  = bx & 31;
    const int h  = (bx >> 5) & 15;
    const int b  = bx >> 9;
    const int shift = (h >= 8) ? 128 : 0;
    const int sbase = g * 256 + shift;   // group-local i -> seq p = (sbase+i)&8191

    const int tid  = threadIdx.x;
    const int wave = tid >> 6;
    const int lane = tid & 63;
    const int quad = lane >> 4;
    const int l15  = lane & 15;

    const size_t bh = ((size_t)b * NHEAD + h) * NSEQ;
    const short* kg = kt + bh * HD;
    const short* vg = vt + bh * HD;

    const int mt0 = wave * 2;            // m-tiles mt0, mt0+1

    // Q fragments from fp32 d_out (A-layout: m=l15, k=quad*8+j)
    short8 qf[2][4];
    for (int im = 0; im < 2; im++) {
        const int row = (mt0 + im) * 16 + l15;
        const int p   = (sbase + row) & (NSEQ - 1);
        const float* qr = qsrc + (((size_t)(b * NSEQ + p)) << 11) + h * HD;
        for (int ks = 0; ks < 4; ks++) {
            const float4v qa = *(const float4v*)(qr + ks * 32 + quad * 8);
            const float4v qb = *(const float4v*)(qr + ks * 32 + quad * 8 + 4);
            short8 f;
            for (int j = 0; j < 4; j++) { f[j] = f2bf(qa[j]); f[4 + j] = f2bf(qb[j]); }
            qf[im][ks] = f;
        }
    }

    const float4v fzero = {0.f, 0.f, 0.f, 0.f};
    float4v o[2][8];
    for (int im = 0; im < 2; im++)
        for (int dt = 0; dt < 8; dt++)
            o[im][dt] = fzero;
    float rs[2][4] = {{0.f, 0.f, 0.f, 0.f}, {0.f, 0.f, 0.f, 0.f}};

    for (int kc = 0; kc < 4; kc++) {
        __syncthreads();
        // stage K chunk: 64 rows x 128 (short8 stores)
        for (int c = 0; c < 2; c++) {
            const int id   = tid + c * 512;
            const int row  = id >> 4;
            const int colb = (id & 15) * 8;
            const int p    = (sbase + kc * 64 + row) & (NSEQ - 1);
            *(short8*)&Ks[row * 136 + colb] = *(const short8*)(kg + (size_t)p * HD + colb);
        }
        // stage V chunk (short4 stores)
        for (int c = 0; c < 4; c++) {
            const int id   = tid + c * 512;
            const int row  = id >> 5;
            const int colb = (id & 31) * 4;
            const int p    = (sbase + kc * 64 + row) & (NSEQ - 1);
            *(short4v*)&Vs[row * 132 + colb] = *(const short4v*)(vg + (size_t)p * HD + colb);
        }
        __syncthreads();

        // scores: full rectangle (mask handles causality)
        float4v s[2][4];
        for (int im = 0; im < 2; im++)
            for (int nn = 0; nn < 4; nn++)
                s[im][nn] = fzero;
        for (int nn = 0; nn < 4; nn++) {
            short8 kf[4];
            for (int ks = 0; ks < 4; ks++)
                kf[ks] = *(const short8*)&Ks[(nn * 16 + l15) * 136 + ks * 32 + quad * 8];
            for (int im = 0; im < 2; im++)
                for (int ks = 0; ks < 4; ks++)
                    s[im][nn] = __builtin_amdgcn_mfma_f32_16x16x32_bf16(
                        qf[im][ks], kf[ks], s[im][nn], 0, 0, 0);
        }

        // exp + P write + PV, per 32-key half
        for (int half = 0; half < 2; half++) {
            for (int im = 0; im < 2; im++) {
                const int qpos = (mt0 + im) * 16 + quad * 4;       // group-abs q row (+r)
                for (int nn2 = 0; nn2 < 2; nn2++) {
                    const int nn   = half * 2 + nn2;
                    const int kpos = kc * 64 + nn * 16 + l15;      // group-abs key
                    for (int r = 0; r < 4; r++) {
                        const float sv = s[im][nn][r] * 0.088388347648318447f;
                        const float pv = (kpos > qpos + r)
                                             ? 0.f
                                             : __expf(fminf(sv, 30.f));
                        rs[im][r] += pv;
                        Ps[wave][(im * 16 + quad * 4 + r) * 40 + nn2 * 16 + l15] = f2bf(pv);
                    }
                }
            }
            __syncthreads();
            short8 pf[2];
            for (int im = 0; im < 2; im++)
                pf[im] = *(const short8*)&Ps[wave][(im * 16 + l15) * 40 + quad * 8];
            for (int dt = 0; dt < 8; dt++) {
                short8 vf;
                for (int jj = 0; jj < 8; jj++)
                    vf[jj] = Vs[(half * 32 + quad * 8 + jj) * 132 + dt * 16 + l15];
                for (int im = 0; im < 2; im++)
                    o[im][dt] = __builtin_amdgcn_mfma_f32_16x16x32_bf16(
                        pf[im], vf, o[im][dt], 0, 0, 0);
            }
            __syncthreads();
        }
    }

    // row sums: reduce across the 16 l15 lanes of each quad
    for (int im = 0; im < 2; im++)
        for (int r = 0; r < 4; r++) {
            float v = rs[im][r];
            v += __shfl_xor(v, 1);
            v += __shfl_xor(v, 2);
            v += __shfl_xor(v, 4);
            v += __shfl_xor(v, 8);
            rs[im][r] = v;
        }

    // write output fp32 [B][N][C]; un-shift == same p mapping
    for (int im = 0; im < 2; im++) {
        for (int r = 0; r < 4; r++) {
            const int row = (mt0 + im) * 16 + quad * 4 + r;
            const int p   = (sbase + row) & (NSEQ - 1);
            const float inv = 1.f / rs[im][r];
            const size_t obase = (((size_t)(b * NSEQ + p)) << 11) + h * HD;
            for (int dt = 0; dt < 8; dt++)
                out[obase + dt * 16 + l15] = o[im][dt][r] * inv;
        }
    }
}

extern "C" void kernel_launch(void* const* d_in, const int* in_sizes, int n_in,
                              void* d_out, int out_size, void* d_ws, size_t ws_size,
                              hipStream_t stream) {
    (void)in_sizes; (void)n_in; (void)out_size; (void)ws_size;
    const float* x  = (const float*)d_in[0];
    const float* Wq = (const float*)d_in[1];
    const float* bq = (const float*)d_in[2];
    const float* Wk = (const float*)d_in[3];
    const float* bk = (const float*)d_in[4];
    const float* Wv = (const float*)d_in[5];
    const float* bv = (const float*)d_in[6];

    // ws layout (bf16 shorts): xb | wqb | wkb | wvb | kt | vt  (~216 MiB)
    short* xb  = (short*)d_ws;
    short* wqb = xb  + (size_t)33554432;
    short* wkb = wqb + (size_t)4194304;
    short* wvb = wkb + (size_t)4194304;
    short* kt  = wvb + (size_t)4194304;
    short* vt  = kt  + (size_t)33554432;

    float* outp = (float*)d_out;

    cvt_all<<<dim3(22528), 256, 0, stream>>>(x, Wq, Wk, Wv, xb, wqb, wkb, wvb);
    qkv_gemm<<<dim3(128, 48), 256, 0, stream>>>(xb, wqb, bq, wkb, bk, wvb, bv,
                                                outp, kt, vt);
    s2_attn<<<dim3(1024), 512, 0, stream>>>(outp, kt, vt, outp);
}